// Round 7
// baseline (4504.715 us; speedup 1.0000x reference)
//
#include <hip/hip_runtime.h>

typedef __attribute__((ext_vector_type(8))) short short8;
typedef __attribute__((ext_vector_type(4))) float f32x4;

__device__ __forceinline__ unsigned short f2bf(float f) {
  union { float f; unsigned u; } v; v.f = f;
  unsigned r = v.u + 0x7fffu + ((v.u >> 16) & 1u);
  return (unsigned short)(r >> 16);
}

__device__ __forceinline__ void async16(const void* g, void* l) {
  __builtin_amdgcn_global_load_lds(
      (const __attribute__((address_space(1))) unsigned*)g,
      (__attribute__((address_space(3))) unsigned*)l, 16, 0, 0);
}

#define SBAR() __builtin_amdgcn_sched_barrier(0)
#define MEMFENCE() asm volatile("" ::: "memory")
#define BARRIER() __builtin_amdgcn_s_barrier()
#define WAIT_VM(N) asm volatile("s_waitcnt vmcnt(" #N ")" ::: "memory")
#define PHASE_END()                                                            \
  do { SBAR(); MEMFENCE(); BARRIER(); SBAR(); MEMFENCE(); } while (0)

// Exact-GELU via Abramowitz-Stegun 7.1.26 erf (|eps| <= 1.5e-7).
__device__ __forceinline__ float gelu_exact(float v) {
  float s = v * 0.70710678118f;
  float x = fabsf(s);
  float t = 1.0f / (1.0f + 0.3275911f * x);
  float p = t * (0.254829592f +
            t * (-0.284496736f +
            t * (1.421413741f + t * (-1.453152027f + t * 1.061405429f))));
  float er = 1.0f - p * __expf(-x * x);
  er = copysignf(er, s);
  return 0.5f * v * (1.0f + er);
}

// ---------------- fp32 -> bf16 bulk convert ----------------
__global__ void cvt_bf16_kernel(const float4* __restrict__ in,
                                ushort4* __restrict__ out, int n4) {
  int i = blockIdx.x * blockDim.x + threadIdx.x;
  int stride = gridDim.x * blockDim.x;
  for (; i < n4; i += stride) {
    float4 v = in[i];
    ushort4 o;
    o.x = f2bf(v.x); o.y = f2bf(v.y); o.z = f2bf(v.z); o.w = f2bf(v.w);
    out[i] = o;
  }
}

// ---------------- W_eff[e] = W + 2.0 * b[e] @ a[e], output bf16 ----------------
__global__ void make_weff(const float* __restrict__ w,
                          const float* __restrict__ bmat,
                          const float* __restrict__ amat,
                          unsigned short* __restrict__ out,
                          int J, int K) {
  const int e = blockIdx.y;
  const float* a = amat + (size_t)e * 64 * K;
  const float* b = bmat + (size_t)e * J * 64;
  const int j0 = blockIdx.x * 16;
  __shared__ float bs[16][64];
  const int tid = threadIdx.x;
  for (int i = tid; i < 16 * 64; i += 256)
    bs[i >> 6][i & 63] = b[(size_t)(j0 + (i >> 6)) * 64 + (i & 63)];
  __syncthreads();
  for (int k = tid; k < K; k += 256) {
    float acc[16];
#pragma unroll
    for (int jj = 0; jj < 16; ++jj) acc[jj] = 0.f;
    for (int r = 0; r < 64; ++r) {
      float av = a[(size_t)r * K + k];
#pragma unroll
      for (int jj = 0; jj < 16; ++jj) acc[jj] += bs[jj][r] * av;
    }
#pragma unroll
    for (int jj = 0; jj < 16; ++jj) {
      float v = w[(size_t)(j0 + jj) * K + k] + 2.0f * acc[jj];
      out[((size_t)e * J + j0 + jj) * K + k] = f2bf(v);
    }
  }
}

// ---------------- 256x256 grouped GEMM, BK=32, 64 KiB LDS, 2 blocks/CU --------
// A: [M][K] bf16, Bw: [2][N][K] bf16 (expert per 256-row M tile), bias f32.
// 8 waves (2M x 4N), per-wave out 128x64. LDS regions As0/As1/Bs0/Bs1, each a
// full 256x32 bf16 K-tile (16 KB), row stride 64 B. Swizzle: 16B slot
// s (0..3) of row r holds global slot s ^ (r&3) (both-sides XOR).
//
// Pipeline (reads one phase ahead into ping-ponged frags; counted lgkm):
//  P1: MFMA(X,X->0,0)  read afmY<-As0[m4]
//  P2: MFMA(Y,X->4,0)  read bfvY<-Bs0[n2]                          [bar]
//  P3: MFMA(X,Y->0,2)  stage As0@t+2                         [vm(2)+bar]
//  P4: MFMA(Y,Y->4,2)  read afmX<-As1[m0], bfvX<-Bs1[n0]           [bar]
//  P5: MFMA(X,X->0,0)  read afmY<-As1[m4]  stage Bs0@t+2
//  P6: MFMA(Y,X->4,0)  read bfvY<-Bs1[n2]                          [bar]
//  P7: MFMA(X,Y->0,2)  stage As1@t+3                         [vm(2)+bar]
//  P8: MFMA(Y,Y->4,2)  read afmX<-As0[m0], bfvX<-Bs0[n0]  stage Bs1@t+3 [bar]
//
// Region last-reads: As0:P1, Bs0:P2, As1:P5, Bs1:P6 -> stages at P3/P5/P7/P8
// are each >=1 runtime barrier after the last reader's lgkm drain (WAR safe).
// FIFO (steady): P3-end queue {As1@t+1,Bs1@t+1,As0@t+2} -> vm(2) drains
// As1/Bs1 (P4's reads). P7-end queue {As0@t+2,Bs0@t+2,As1@t+3} -> vm(2)
// drains As0/Bs0 (P8's reads). Prologue (8 loads, vm(4)) enters steady state.

#define STAGE(Xp, Xs, ob)                                                      \
  do {                                                                         \
    const char* _g = (const char*)(Xp) + gbyte + (ob);                         \
    async16(_g, (Xs) + loff);                                                  \
    async16(_g + (size_t)K * 32, (Xs) + loff + 512);                           \
  } while (0)

#define RDA_TO(dst, Xs, mbase)                                                 \
  _Pragma("unroll") for (int m_ = 0; m_ < 4; ++m_)                             \
      dst[m_] = *(const short8*)((const char*)(Xs) + arowB +                   \
                                 ((mbase) + m_) * 1024 + cbv);

#define RDB_TO(dst, Xs, nbase)                                                 \
  _Pragma("unroll") for (int n_ = 0; n_ < 2; ++n_)                             \
      dst[n_] = *(const short8*)((const char*)(Xs) + browB +                   \
                                 ((nbase) + n_) * 1024 + cbv);

#define MFMAQ(af, bf, mbase, nbase)                                            \
  __builtin_amdgcn_s_setprio(1);                                               \
  _Pragma("unroll") for (int m_ = 0; m_ < 4; ++m_)                             \
  _Pragma("unroll") for (int n_ = 0; n_ < 2; ++n_)                             \
      acc[(mbase) + m_][(nbase) + n_] =                                        \
          __builtin_amdgcn_mfma_f32_16x16x32_bf16(                             \
              af[m_], bf[n_], acc[(mbase) + m_][(nbase) + n_], 0, 0, 0);       \
  __builtin_amdgcn_s_setprio(0);

template <bool FUSE_GELU, bool OUT_BF16>
__global__ __launch_bounds__(512, 4) void gemm256(
    const unsigned short* __restrict__ A, const unsigned short* __restrict__ Bw,
    const float* __restrict__ bias, void* __restrict__ Cout, int N, int K,
    int NXT) {
  extern __shared__ unsigned short lds[];
  unsigned short* As0 = lds;             // 16 KB each
  unsigned short* As1 = lds + 8192;
  unsigned short* Bs0 = lds + 16384;
  unsigned short* Bs1 = lds + 24576;

  const int tid = threadIdx.x;
  const int w = tid >> 6, lane = tid & 63;

  // XCD-aware bijective swizzle (gridDim.x % 8 == 0 by construction)
  const int nwg = gridDim.x, bid = blockIdx.x;
  const int qchunk = nwg >> 3;
  const int wg = (bid & 7) * qchunk + (bid >> 3);
  const int by = wg / NXT, bx = wg - by * NXT;
  const int m0 = by << 8, n0 = bx << 8;
  const int e = (m0 % 1280) ? 1 : 0;  // 256-aligned tiles never span experts
  const unsigned short* Ap = A + (size_t)m0 * K;
  const unsigned short* Bp = Bw + ((size_t)e * N + n0) * K;

  const int wr = w >> 2, wc = w & 3;
  const int fr = lane & 15;
  const int cbv = (((lane >> 4) ^ (fr & 3)) << 4);  // swizzled slot byte
  const int arowB = (wr * 128 + fr) * 64;  // byte base of A frag rows
  const int browB = (wc * 64 + fr) * 64;   // byte base of B frag rows

  // staging: seg0 covers rows w*32+(lane>>2), seg1 +16; slot (lane&3) holds
  // global slot (lane&3)^(row&3); LDS dest linear (HW adds lane*16B).
  const int srow = w * 32 + (lane >> 2);
  const int sslot = (lane & 3) ^ ((lane >> 2) & 3);
  const size_t gbyte = (size_t)srow * K * 2 + sslot * 16;
  const int loff = w * 1024;  // elements; seg1 adds 512

  f32x4 acc[8][4] = {};
  short8 afmX[4], afmY[4], bfvX[2], bfvY[2];

  const int T = K >> 5;     // 32-wide K tiles (24 or 96, even)
  const int niter = T >> 1;
  const int KB2 = K << 1;   // bytes per row (wrap modulus)

  // ---- prologue: {As0,Bs0}@t0, {As1,Bs1}@t1 in flight ----
  STAGE(Ap, As0, 0); STAGE(Bp, Bs0, 0);
  STAGE(Ap, As1, 64); STAGE(Bp, Bs1, 64);
  SBAR(); WAIT_VM(4); SBAR();
  MEMFENCE(); BARRIER(); SBAR(); MEMFENCE();
  RDA_TO(afmX, As0, 0); RDB_TO(bfvX, Bs0, 0);

  int ob2 = 128, ob3 = 192;
  if (ob2 >= KB2) ob2 -= KB2;
  if (ob3 >= KB2) ob3 -= KB2;

  for (int i = 0; i < niter; ++i) {
    // P1: MFMA(0,0) buf0; read afmY<-As0[m4]
    RDA_TO(afmY, As0, 4);
    SBAR();
    MFMAQ(afmX, bfvX, 0, 0);
    SBAR();
    // P2: MFMA(4,0); read bfvY<-Bs0[n2]; barrier
    RDB_TO(bfvY, Bs0, 2);
    SBAR();
    MFMAQ(afmY, bfvX, 4, 0);
    PHASE_END();
    // P3: MFMA(0,2); stage As0@t+2; vm(2)+barrier
    STAGE(Ap, As0, ob2);
    SBAR();
    MFMAQ(afmX, bfvY, 0, 2);
    SBAR(); WAIT_VM(2);
    PHASE_END();
    // P4: MFMA(4,2); read afmX<-As1[m0], bfvX<-Bs1[n0]; barrier
    RDA_TO(afmX, As1, 0); RDB_TO(bfvX, Bs1, 0);
    SBAR();
    MFMAQ(afmY, bfvY, 4, 2);
    PHASE_END();
    // P5: MFMA(0,0) buf1; read afmY<-As1[m4]; stage Bs0@t+2
    RDA_TO(afmY, As1, 4);
    STAGE(Bp, Bs0, ob2);
    SBAR();
    MFMAQ(afmX, bfvX, 0, 0);
    SBAR();
    // P6: MFMA(4,0); read bfvY<-Bs1[n2]; barrier
    RDB_TO(bfvY, Bs1, 2);
    SBAR();
    MFMAQ(afmY, bfvX, 4, 0);
    PHASE_END();
    // P7: MFMA(0,2); stage As1@t+3; vm(2)+barrier
    STAGE(Ap, As1, ob3);
    SBAR();
    MFMAQ(afmX, bfvY, 0, 2);
    SBAR(); WAIT_VM(2);
    PHASE_END();
    // P8: MFMA(4,2); read afmX<-As0[m0]@t+2, bfvX<-Bs0[n0]@t+2;
    //     stage Bs1@t+3 (Bs1 last read P6, drained before P7 MFMA, bar P7-end)
    RDA_TO(afmX, As0, 0); RDB_TO(bfvX, Bs0, 0);
    STAGE(Bp, Bs1, ob3);
    SBAR();
    MFMAQ(afmY, bfvY, 4, 2);
    PHASE_END();

    ob2 += 128; if (ob2 >= KB2) ob2 -= KB2;
    ob3 += 128; if (ob3 >= KB2) ob3 -= KB2;
  }

  // ---- epilogue: C/D layout col=lane&15, row=(lane>>4)*4+j ----
  const int lrow = (lane >> 4) << 2;
#pragma unroll
  for (int mi = 0; mi < 8; ++mi) {
    const int rbase = m0 + wr * 128 + mi * 16 + lrow;
#pragma unroll
    for (int n = 0; n < 4; ++n) {
      const int col = n0 + wc * 64 + n * 16 + fr;
      const float bv = bias[col];
#pragma unroll
      for (int j = 0; j < 4; ++j) {
        const int row = rbase + j;
        float v = acc[mi][n][j] + bv;
        if (FUSE_GELU) v = gelu_exact(v);
        if (OUT_BF16)
          ((unsigned short*)Cout)[(size_t)row * N + col] = f2bf(v);
        else
          ((float*)Cout)[(size_t)row * N + col] = v;
      }
    }
  }
}

extern "C" void kernel_launch(void* const* d_in, const int* in_sizes, int n_in,
                              void* d_out, int out_size, void* d_ws,
                              size_t ws_size, hipStream_t stream) {
  const float* x = (const float*)d_in[0];
  const float* w1 = (const float*)d_in[1];
  const float* bias1 = (const float*)d_in[2];
  const float* a1 = (const float*)d_in[3];
  const float* b1 = (const float*)d_in[4];
  const float* w2 = (const float*)d_in[5];
  const float* bias2 = (const float*)d_in[6];
  const float* a2 = (const float*)d_in[7];
  const float* b2 = (const float*)d_in[8];
  float* out = (float*)d_out;

  char* ws = (char*)d_ws;
  unsigned short* x_bf = (unsigned short*)(ws + 0);        // 40960*768 bf16
  unsigned short* w1e = (unsigned short*)(ws + 62914560);  // 2*3072*768 bf16
  unsigned short* w2e = (unsigned short*)(ws + 72351744);  // 2*768*3072 bf16
  unsigned short* h = (unsigned short*)(ws + 81788928);    // 40960*3072 bf16

  hipFuncSetAttribute(reinterpret_cast<const void*>(&gemm256<true, true>),
                      hipFuncAttributeMaxDynamicSharedMemorySize, 65536);
  hipFuncSetAttribute(reinterpret_cast<const void*>(&gemm256<false, false>),
                      hipFuncAttributeMaxDynamicSharedMemorySize, 65536);

  cvt_bf16_kernel<<<4096, 256, 0, stream>>>((const float4*)x, (ushort4*)x_bf,
                                            40960 * 768 / 4);
  make_weff<<<dim3(3072 / 16, 2), 256, 0, stream>>>(w1, b1, a1, w1e, 3072, 768);
  make_weff<<<dim3(768 / 16, 2), 256, 0, stream>>>(w2, b2, a2, w2e, 768, 3072);

  // M=40960 -> 160 M-tiles; GEMM1: 160x12=1920 wgs; GEMM2: 160x3=480 wgs
  gemm256<true, true><<<1920, 512, 65536, stream>>>(x_bf, w1e, bias1, h, 3072,
                                                    768, 12);
  gemm256<false, false><<<480, 512, 65536, stream>>>(h, w2e, bias2, out, 768,
                                                     3072, 3);
}

// Round 8
// 754.697 us; speedup vs baseline: 5.9689x; 5.9689x over previous
//
#include <hip/hip_runtime.h>

typedef __attribute__((ext_vector_type(8))) short short8;
typedef __attribute__((ext_vector_type(4))) float f32x4;

__device__ __forceinline__ unsigned short f2bf(float f) {
  union { float f; unsigned u; } v; v.f = f;
  unsigned r = v.u + 0x7fffu + ((v.u >> 16) & 1u);
  return (unsigned short)(r >> 16);
}

__device__ __forceinline__ void async16(const void* g, void* l) {
  __builtin_amdgcn_global_load_lds(
      (const __attribute__((address_space(1))) unsigned*)g,
      (__attribute__((address_space(3))) unsigned*)l, 16, 0, 0);
}

#define MEMFENCE() asm volatile("" ::: "memory")
#define BARRIER() __builtin_amdgcn_s_barrier()
#define WAIT_VM(N) asm volatile("s_waitcnt vmcnt(" #N ")" ::: "memory")

// Exact-GELU via Abramowitz-Stegun 7.1.26 erf (|eps| <= 1.5e-7).
__device__ __forceinline__ float gelu_exact(float v) {
  float s = v * 0.70710678118f;
  float x = fabsf(s);
  float t = 1.0f / (1.0f + 0.3275911f * x);
  float p = t * (0.254829592f +
            t * (-0.284496736f +
            t * (1.421413741f + t * (-1.453152027f + t * 1.061405429f))));
  float er = 1.0f - p * __expf(-x * x);
  er = copysignf(er, s);
  return 0.5f * v * (1.0f + er);
}

// ---------------- fp32 -> bf16 bulk convert ----------------
__global__ void cvt_bf16_kernel(const float4* __restrict__ in,
                                ushort4* __restrict__ out, int n4) {
  int i = blockIdx.x * blockDim.x + threadIdx.x;
  int stride = gridDim.x * blockDim.x;
  for (; i < n4; i += stride) {
    float4 v = in[i];
    ushort4 o;
    o.x = f2bf(v.x); o.y = f2bf(v.y); o.z = f2bf(v.z); o.w = f2bf(v.w);
    out[i] = o;
  }
}

// ---------------- W_eff[e] = W + 2.0 * b[e] @ a[e], output bf16 ----------------
__global__ void make_weff(const float* __restrict__ w,
                          const float* __restrict__ bmat,
                          const float* __restrict__ amat,
                          unsigned short* __restrict__ out,
                          int J, int K) {
  const int e = blockIdx.y;
  const float* a = amat + (size_t)e * 64 * K;
  const float* b = bmat + (size_t)e * J * 64;
  const int j0 = blockIdx.x * 16;
  __shared__ float bs[16][64];
  const int tid = threadIdx.x;
  for (int i = tid; i < 16 * 64; i += 256)
    bs[i >> 6][i & 63] = b[(size_t)(j0 + (i >> 6)) * 64 + (i & 63)];
  __syncthreads();
  for (int k = tid; k < K; k += 256) {
    float acc[16];
#pragma unroll
    for (int jj = 0; jj < 16; ++jj) acc[jj] = 0.f;
    for (int r = 0; r < 64; ++r) {
      float av = a[(size_t)r * K + k];
#pragma unroll
      for (int jj = 0; jj < 16; ++jj) acc[jj] += bs[jj][r] * av;
    }
#pragma unroll
    for (int jj = 0; jj < 16; ++jj) {
      float v = w[(size_t)(j0 + jj) * K + k] + 2.0f * acc[jj];
      out[((size_t)e * J + j0 + jj) * K + k] = f2bf(v);
    }
  }
}

// ---------------- 256x128 grouped GEMM, BK=32, 72 KiB LDS, 2 blocks/CU --------
// A: [M][K] bf16, Bw: [2][N][K] bf16 (expert per 256-row M tile), bias f32.
// 8 waves (4M x 2N), per-wave out 64x64 -> acc[4][4] = 64 regs (fits 128-reg
// cap at 4 waves/EU). Triple-buffered LDS: A 3x16KB + B 3x8KB = 72 KB;
// 2 blocks/CU = 144 KiB <= 160. Cross-block TLP hides phase stalls.
//
// LDS image per buf: [rows][4 x 16B slots], row stride 64 B. Swizzle: LDS
// slot s holds global slot s ^ ((row>>1)&3) -> fragment reads are 2-way
// bank aliased only (free, m136). Staged via pre-swizzled global source.
//
// Loop (per 32-wide K-tile t): stage t+2 into free buf (3 async16) ->
// read 8 frags from cur buf (counted lgkm before MFMA) -> 16 MFMA ->
// WAIT_VM(3) (drains tile t+1, leaves t+2 in flight - never 0) -> barrier ->
// rotate. WAR on free buf: its reads drained before prev barrier.

#define STAGE_A(Xs, ob)                                                        \
  do {                                                                         \
    const char* _g = (const char*)Ap + gbyte + (ob);                           \
    async16(_g, (Xs) + loff);                                                  \
    async16(_g + (size_t)K * 256, (Xs) + loff + 4096);                         \
  } while (0)
#define STAGE_B(Xs, ob) async16((const char*)Bp + gbyte + (ob), (Xs) + loff)

template <bool FUSE_GELU, bool OUT_BF16>
__global__ __launch_bounds__(512, 4) void gemm128(
    const unsigned short* __restrict__ A, const unsigned short* __restrict__ Bw,
    const float* __restrict__ bias, void* __restrict__ Cout, int N, int K,
    int NXT) {
  extern __shared__ unsigned short lds[];
  unsigned short* Abuf0 = lds;           // 8192 elems (16 KB) each
  unsigned short* Abuf1 = lds + 8192;
  unsigned short* Abuf2 = lds + 16384;
  unsigned short* Bbuf0 = lds + 24576;   // 4096 elems (8 KB) each
  unsigned short* Bbuf1 = lds + 28672;
  unsigned short* Bbuf2 = lds + 32768;

  const int tid = threadIdx.x;
  const int w = tid >> 6, lane = tid & 63;

  // XCD-aware bijective swizzle (gridDim.x % 8 == 0 by construction)
  const int nwg = gridDim.x, bid = blockIdx.x;
  const int qchunk = nwg >> 3;
  const int wg = (bid & 7) * qchunk + (bid >> 3);
  const int by = wg / NXT, bx = wg - by * NXT;
  const int m0 = by << 8, n0 = bx << 7;
  const int e = (m0 % 1280) ? 1 : 0;  // 256-aligned tiles never span experts
  const unsigned short* Ap = A + (size_t)m0 * K;
  const unsigned short* Bp = Bw + ((size_t)e * N + n0) * K;

  const int wr = w >> 1, wc = w & 1;
  const int fr = lane & 15;
  const int cbv = (((lane >> 4) ^ ((fr >> 1) & 3)) << 4);  // swizzled slot
  const int arowB = (wr * 64 + fr) * 64;  // byte base of A frag rows
  const int browB = (wc * 64 + fr) * 64;  // byte base of B frag rows

  // staging: thread -> row w*16+(lane>>2), global slot (lane&3)^((row>>1)&3)
  // ((row>>1)&3 == (lane>>3)&3 here); LDS dest linear (HW adds lane*16B).
  const int sslot = (lane & 3) ^ ((lane >> 3) & 3);
  const size_t gbyte = (size_t)(w * 16 + (lane >> 2)) * K * 2 + sslot * 16;
  const int loff = w * 512;  // elements; A second half adds 4096

  f32x4 acc[4][4] = {};
  short8 afm[4], bfv[4];

  const int T = K >> 5;    // 32-wide K tiles (24 or 96)
  const int KB2 = K << 1;  // bytes per row (wrap modulus)

  unsigned short *Ac = Abuf0, *An = Abuf1, *Af = Abuf2;
  unsigned short *Bc = Bbuf0, *Bn = Bbuf1, *Bf = Bbuf2;

  // ---- prologue: tiles 0,1 in flight; drain tile 0 ----
  STAGE_A(Abuf0, 0); STAGE_B(Bbuf0, 0);
  STAGE_A(Abuf1, 64); STAGE_B(Bbuf1, 64);
  WAIT_VM(3); MEMFENCE(); BARRIER(); MEMFENCE();

  int ob = 128;  // byte offset of tile t+2 (K>=768 so no initial wrap)

  for (int t = 0; t < T; ++t) {
    // stage tile t+2 into free buffers (wraps to garbage refetch at tail)
    STAGE_A(Af, ob); STAGE_B(Bf, ob);
    // fragment reads from current tile
#pragma unroll
    for (int m_ = 0; m_ < 4; ++m_)
      afm[m_] = *(const short8*)((const char*)Ac + arowB + m_ * 1024 + cbv);
#pragma unroll
    for (int n_ = 0; n_ < 4; ++n_)
      bfv[n_] = *(const short8*)((const char*)Bc + browB + n_ * 1024 + cbv);
    __builtin_amdgcn_s_setprio(1);
#pragma unroll
    for (int m_ = 0; m_ < 4; ++m_)
#pragma unroll
      for (int n_ = 0; n_ < 4; ++n_)
        acc[m_][n_] = __builtin_amdgcn_mfma_f32_16x16x32_bf16(
            afm[m_], bfv[n_], acc[m_][n_], 0, 0, 0);
    __builtin_amdgcn_s_setprio(0);
    // tile t+1 must land; t+2's 3 loads stay in flight (never vmcnt 0)
    WAIT_VM(3); MEMFENCE(); BARRIER(); MEMFENCE();
    // rotate buffers
    unsigned short* tA = Ac; Ac = An; An = Af; Af = tA;
    unsigned short* tB = Bc; Bc = Bn; Bn = Bf; Bf = tB;
    ob += 64; if (ob >= KB2) ob -= KB2;
  }

  // ---- epilogue: C/D layout col=lane&15, row=(lane>>4)*4+j ----
  const int lrow = (lane >> 4) << 2;
#pragma unroll
  for (int mi = 0; mi < 4; ++mi) {
    const int rbase = m0 + wr * 64 + mi * 16 + lrow;
#pragma unroll
    for (int n = 0; n < 4; ++n) {
      const int col = n0 + wc * 64 + n * 16 + fr;
      const float bv = bias[col];
#pragma unroll
      for (int j = 0; j < 4; ++j) {
        const int row = rbase + j;
        float v = acc[mi][n][j] + bv;
        if (FUSE_GELU) v = gelu_exact(v);
        if (OUT_BF16)
          ((unsigned short*)Cout)[(size_t)row * N + col] = f2bf(v);
        else
          ((float*)Cout)[(size_t)row * N + col] = v;
      }
    }
  }
}

extern "C" void kernel_launch(void* const* d_in, const int* in_sizes, int n_in,
                              void* d_out, int out_size, void* d_ws,
                              size_t ws_size, hipStream_t stream) {
  const float* x = (const float*)d_in[0];
  const float* w1 = (const float*)d_in[1];
  const float* bias1 = (const float*)d_in[2];
  const float* a1 = (const float*)d_in[3];
  const float* b1 = (const float*)d_in[4];
  const float* w2 = (const float*)d_in[5];
  const float* bias2 = (const float*)d_in[6];
  const float* a2 = (const float*)d_in[7];
  const float* b2 = (const float*)d_in[8];
  float* out = (float*)d_out;

  char* ws = (char*)d_ws;
  unsigned short* x_bf = (unsigned short*)(ws + 0);        // 40960*768 bf16
  unsigned short* w1e = (unsigned short*)(ws + 62914560);  // 2*3072*768 bf16
  unsigned short* w2e = (unsigned short*)(ws + 72351744);  // 2*768*3072 bf16
  unsigned short* h = (unsigned short*)(ws + 81788928);    // 40960*3072 bf16

  hipFuncSetAttribute(reinterpret_cast<const void*>(&gemm128<true, true>),
                      hipFuncAttributeMaxDynamicSharedMemorySize, 73728);
  hipFuncSetAttribute(reinterpret_cast<const void*>(&gemm128<false, false>),
                      hipFuncAttributeMaxDynamicSharedMemorySize, 73728);

  cvt_bf16_kernel<<<4096, 256, 0, stream>>>((const float4*)x, (ushort4*)x_bf,
                                            40960 * 768 / 4);
  make_weff<<<dim3(3072 / 16, 2), 256, 0, stream>>>(w1, b1, a1, w1e, 3072, 768);
  make_weff<<<dim3(768 / 16, 2), 256, 0, stream>>>(w2, b2, a2, w2e, 768, 3072);

  // M=40960 -> 160 M-tiles; GEMM1: 160x24=3840 wgs; GEMM2: 160x6=960 wgs
  gemm128<true, true><<<3840, 512, 73728, stream>>>(x_bf, w1e, bias1, h, 3072,
                                                    768, 24);
  gemm128<false, false><<<960, 512, 73728, stream>>>(h, w2e, bias2, out, 768,
                                                     3072, 6);
}

// Round 11
// 744.105 us; speedup vs baseline: 6.0539x; 1.0142x over previous
//
#include <hip/hip_runtime.h>

typedef __attribute__((ext_vector_type(8))) short short8;
typedef __attribute__((ext_vector_type(4))) float f32x4;

__device__ __forceinline__ unsigned short f2bf(float f) {
  union { float f; unsigned u; } v; v.f = f;
  unsigned r = v.u + 0x7fffu + ((v.u >> 16) & 1u);
  return (unsigned short)(r >> 16);
}

__device__ __forceinline__ void async16(const void* g, void* l) {
  __builtin_amdgcn_global_load_lds(
      (const __attribute__((address_space(1))) unsigned*)g,
      (__attribute__((address_space(3))) unsigned*)l, 16, 0, 0);
}

#define MEMFENCE() asm volatile("" ::: "memory")
#define BARRIER() __builtin_amdgcn_s_barrier()
#define WAIT_VM(N) asm volatile("s_waitcnt vmcnt(" #N ")" ::: "memory")

// Exact-GELU via Abramowitz-Stegun 7.1.26 erf (|eps| <= 1.5e-7).
__device__ __forceinline__ float gelu_exact(float v) {
  float s = v * 0.70710678118f;
  float x = fabsf(s);
  float t = 1.0f / (1.0f + 0.3275911f * x);
  float p = t * (0.254829592f +
            t * (-0.284496736f +
            t * (1.421413741f + t * (-1.453152027f + t * 1.061405429f))));
  float er = 1.0f - p * __expf(-x * x);
  er = copysignf(er, s);
  return 0.5f * v * (1.0f + er);
}

// ---------------- fp32 -> bf16 bulk convert ----------------
__global__ void cvt_bf16_kernel(const float4* __restrict__ in,
                                ushort4* __restrict__ out, int n4) {
  int i = blockIdx.x * blockDim.x + threadIdx.x;
  int stride = gridDim.x * blockDim.x;
  for (; i < n4; i += stride) {
    float4 v = in[i];
    ushort4 o;
    o.x = f2bf(v.x); o.y = f2bf(v.y); o.z = f2bf(v.z); o.w = f2bf(v.w);
    out[i] = o;
  }
}

// ---------------- W_eff[e] = W + 2.0 * b[e] @ a[e], output bf16 ----------------
__global__ void make_weff(const float* __restrict__ w,
                          const float* __restrict__ bmat,
                          const float* __restrict__ amat,
                          unsigned short* __restrict__ out,
                          int J, int K) {
  const int e = blockIdx.y;
  const float* a = amat + (size_t)e * 64 * K;
  const float* b = bmat + (size_t)e * J * 64;
  const int j0 = blockIdx.x * 16;
  __shared__ float bs[16][64];
  const int tid = threadIdx.x;
  for (int i = tid; i < 16 * 64; i += 256)
    bs[i >> 6][i & 63] = b[(size_t)(j0 + (i >> 6)) * 64 + (i & 63)];
  __syncthreads();
  for (int k = tid; k < K; k += 256) {
    float acc[16];
#pragma unroll
    for (int jj = 0; jj < 16; ++jj) acc[jj] = 0.f;
    for (int r = 0; r < 64; ++r) {
      float av = a[(size_t)r * K + k];
#pragma unroll
      for (int jj = 0; jj < 16; ++jj) acc[jj] += bs[jj][r] * av;
    }
#pragma unroll
    for (int jj = 0; jj < 16; ++jj) {
      float v = w[(size_t)(j0 + jj) * K + k] + 2.0f * acc[jj];
      out[((size_t)e * J + j0 + jj) * K + k] = f2bf(v);
    }
  }
}

// ---------------- 256x128 grouped GEMM, 4 waves, BK=32, 2 blocks/CU -----------
// A: [M][K] bf16, Bw: [2][N][K] bf16 (expert per 256-row M tile), bias f32.
// 4 waves (2M x 2N), per-wave out 128x64 -> 384 B LDS read per MFMA.
// acc[8][4]=128 VGPR + frags 48 (~200 total, cap 256 at 2 waves/SIMD).
// Triple-buffered LDS: A 3x16KB + B 3x8KB = 72 KB; 2 blocks/CU for TLP.
// Swizzle: 16B slot s of row r holds global slot s ^ ((r>>1)&3) (2-way only).
// Slot J (static x3 unroll): stage tile t+2 into buf (J+2)%3 (6 async16,
// plain pointers, builtin offset never used), 12 ds_read (base+imm), 32 MFMA,
// WAIT_VM(6) (tile t+1 landed, t+2 in flight), barrier.
// PROLOGUE ORDER MATTERS: all 6 tile-0 loads FIRST, then tile-1's 6, so
// WAIT_VM(6) drains exactly tile 0 (round-10 bug: interleaved order left
// tile-0's A3/B loads in flight at first read).

#define SLOT(J, a0, a1, a2, a3, b0, b1)                                        \
  do {                                                                         \
    constexpr int SD = ((J) + 2) % 3;                                          \
    constexpr int GO = (J) * 64 + 128;                                         \
    async16(a0 + GO, ldsA + SD * 8192 + ldst);                                 \
    async16(a1 + GO, ldsA + SD * 8192 + 2048 + ldst);                          \
    async16(a2 + GO, ldsA + SD * 8192 + 4096 + ldst);                          \
    async16(a3 + GO, ldsA + SD * 8192 + 6144 + ldst);                          \
    async16(b0 + GO, ldsB + SD * 4096 + ldst);                                 \
    async16(b1 + GO, ldsB + SD * 4096 + 2048 + ldst);                          \
    short8 afm[8], bfv[4];                                                     \
    _Pragma("unroll") for (int n_ = 0; n_ < 4; ++n_)                           \
        bfv[n_] = *(const short8*)(bRd + (J) * 8192 + n_ * 1024);              \
    _Pragma("unroll") for (int m_ = 0; m_ < 8; ++m_)                           \
        afm[m_] = *(const short8*)(aRd + (J) * 16384 + m_ * 1024);             \
    __builtin_amdgcn_s_setprio(1);                                             \
    _Pragma("unroll") for (int m_ = 0; m_ < 8; ++m_)                           \
    _Pragma("unroll") for (int n_ = 0; n_ < 4; ++n_)                           \
        acc[m_][n_] = __builtin_amdgcn_mfma_f32_16x16x32_bf16(                 \
            afm[m_], bfv[n_], acc[m_][n_], 0, 0, 0);                           \
    __builtin_amdgcn_s_setprio(0);                                             \
    WAIT_VM(6); MEMFENCE(); BARRIER(); MEMFENCE();                             \
  } while (0)

template <bool FUSE_GELU, bool OUT_BF16>
__global__ __launch_bounds__(256, 2) void gemm128(
    const unsigned short* __restrict__ A, const unsigned short* __restrict__ Bw,
    const float* __restrict__ bias, void* __restrict__ Cout, int N, int K,
    int NXT) {
  extern __shared__ unsigned short lds[];
  unsigned short* ldsA = lds;            // 3 x 8192 elems (16 KB)
  unsigned short* ldsB = lds + 24576;    // 3 x 4096 elems (8 KB)

  const int tid = threadIdx.x;           // 0..255
  const int w = tid >> 6, lane = tid & 63;

  // XCD-aware bijective swizzle (gridDim.x % 8 == 0 by construction)
  const int nwg = gridDim.x, bid = blockIdx.x;
  const int qchunk = nwg >> 3;
  const int wg = (bid & 7) * qchunk + (bid >> 3);
  const int by = wg / NXT, bx = wg - by * NXT;
  const int m0 = by << 8, n0 = bx << 7;
  const int e = (m0 % 1280) ? 1 : 0;  // 256-aligned tiles never span experts
  const unsigned short* Ap = A + (size_t)m0 * K;
  const unsigned short* Bp = Bw + ((size_t)e * N + n0) * K;

  const int wr = w >> 1, wc = w & 1;
  const int fr = lane & 15;
  const int cbv = (((lane >> 4) ^ ((fr >> 1) & 3)) << 4);  // swizzled slot
  const char* aRd = (const char*)lds + (wr * 128 + fr) * 64 + cbv;
  const char* bRd = (const char*)lds + 49152 + (wc * 64 + fr) * 64 + cbv;

  // staging: thread -> row tid>>2 (within 64-row panel), slot
  // (tid&3)^((tid>>3)&3); LDS dest linear (HW adds lane*16B).
  const int sslot = (tid & 3) ^ ((tid >> 3) & 3);
  const size_t grow = (size_t)(tid >> 2) * K * 2 + sslot * 16;
  const size_t KP = (size_t)K * 128;  // 64 rows of bytes
  const char* gA0 = (const char*)Ap + grow;
  const char* gA1 = gA0 + KP;
  const char* gA2 = gA0 + 2 * KP;
  const char* gA3 = gA0 + 3 * KP;
  const char* gB0 = (const char*)Bp + grow;
  const char* gB1 = gB0 + KP;
  const int ldst = w * 512;  // wave-uniform element base (HW adds lane*16B)

  f32x4 acc[8][4] = {};

  const int T = K >> 5;    // 32-wide K tiles (24 or 96; divisible by 3)
  const int G = T / 3;
  const int KB2 = K << 1;  // bytes per row

  // ---- prologue: tile 0's SIX loads first, then tile 1's six ----
  async16(gA0, ldsA + ldst);
  async16(gA1, ldsA + 2048 + ldst);
  async16(gA2, ldsA + 4096 + ldst);
  async16(gA3, ldsA + 6144 + ldst);
  async16(gB0, ldsB + ldst);
  async16(gB1, ldsB + 2048 + ldst);
  async16(gA0 + 64, ldsA + 8192 + ldst);
  async16(gA1 + 64, ldsA + 10240 + ldst);
  async16(gA2 + 64, ldsA + 12288 + ldst);
  async16(gA3 + 64, ldsA + 14336 + ldst);
  async16(gB0 + 64, ldsB + 4096 + ldst);
  async16(gB1 + 64, ldsB + 6144 + ldst);
  WAIT_VM(6); MEMFENCE(); BARRIER(); MEMFENCE();

  for (int g = 0; g < G - 1; ++g) {
    SLOT(0, gA0, gA1, gA2, gA3, gB0, gB1);
    SLOT(1, gA0, gA1, gA2, gA3, gB0, gB1);
    SLOT(2, gA0, gA1, gA2, gA3, gB0, gB1);
    gA0 += 192; gA1 += 192; gA2 += 192; gA3 += 192; gB0 += 192; gB1 += 192;
  }
  {  // peeled last group: slots 1,2 stage tiles T,T+1 -> wrap (never read)
    SLOT(0, gA0, gA1, gA2, gA3, gB0, gB1);
    const char* wA0 = gA0 - KB2; const char* wA1 = gA1 - KB2;
    const char* wA2 = gA2 - KB2; const char* wA3 = gA3 - KB2;
    const char* wB0 = gB0 - KB2; const char* wB1 = gB1 - KB2;
    SLOT(1, wA0, wA1, wA2, wA3, wB0, wB1);
    SLOT(2, wA0, wA1, wA2, wA3, wB0, wB1);
  }

  // ---- epilogue: C/D layout col=lane&15, row=(lane>>4)*4+j ----
  const int lrow = (lane >> 4) << 2;
#pragma unroll
  for (int mi = 0; mi < 8; ++mi) {
    const int rbase = m0 + wr * 128 + mi * 16 + lrow;
#pragma unroll
    for (int n = 0; n < 4; ++n) {
      const int col = n0 + wc * 64 + n * 16 + fr;
      const float bv = bias[col];
#pragma unroll
      for (int j = 0; j < 4; ++j) {
        const int row = rbase + j;
        float v = acc[mi][n][j] + bv;
        if (FUSE_GELU) v = gelu_exact(v);
        if (OUT_BF16)
          ((unsigned short*)Cout)[(size_t)row * N + col] = f2bf(v);
        else
          ((float*)Cout)[(size_t)row * N + col] = v;
      }
    }
  }
}

extern "C" void kernel_launch(void* const* d_in, const int* in_sizes, int n_in,
                              void* d_out, int out_size, void* d_ws,
                              size_t ws_size, hipStream_t stream) {
  const float* x = (const float*)d_in[0];
  const float* w1 = (const float*)d_in[1];
  const float* bias1 = (const float*)d_in[2];
  const float* a1 = (const float*)d_in[3];
  const float* b1 = (const float*)d_in[4];
  const float* w2 = (const float*)d_in[5];
  const float* bias2 = (const float*)d_in[6];
  const float* a2 = (const float*)d_in[7];
  const float* b2 = (const float*)d_in[8];
  float* out = (float*)d_out;

  char* ws = (char*)d_ws;
  unsigned short* x_bf = (unsigned short*)(ws + 0);        // 40960*768 bf16
  unsigned short* w1e = (unsigned short*)(ws + 62914560);  // 2*3072*768 bf16
  unsigned short* w2e = (unsigned short*)(ws + 72351744);  // 2*768*3072 bf16
  unsigned short* h = (unsigned short*)(ws + 81788928);    // 40960*3072 bf16

  hipFuncSetAttribute(reinterpret_cast<const void*>(&gemm128<true, true>),
                      hipFuncAttributeMaxDynamicSharedMemorySize, 73728);
  hipFuncSetAttribute(reinterpret_cast<const void*>(&gemm128<false, false>),
                      hipFuncAttributeMaxDynamicSharedMemorySize, 73728);

  cvt_bf16_kernel<<<4096, 256, 0, stream>>>((const float4*)x, (ushort4*)x_bf,
                                            40960 * 768 / 4);
  make_weff<<<dim3(3072 / 16, 2), 256, 0, stream>>>(w1, b1, a1, w1e, 3072, 768);
  make_weff<<<dim3(768 / 16, 2), 256, 0, stream>>>(w2, b2, a2, w2e, 768, 3072);

  // M=40960 -> 160 M-tiles; GEMM1: 160x24=3840 wgs; GEMM2: 160x6=960 wgs
  gemm128<true, true><<<3840, 256, 73728, stream>>>(x_bf, w1e, bias1, h, 3072,
                                                    768, 24);
  gemm128<false, false><<<960, 256, 73728, stream>>>(h, w2e, bias2, out, 768,
                                                     3072, 6);
}